// Round 3
// baseline (788.312 us; speedup 1.0000x reference)
//
#include <hip/hip_runtime.h>

#define NB 8
#define NC 64
#define NN 4096
#define NO 64
#define KK 20
#define EPSV 1e-5f
#define SLOPE 0.2f
#define CAP 80

// ws layout (float units):
// y1 : [B][N][O]   off 0         (2097152)
// y2 : [B][N][O]   off 2097152
// xx : [B][N]      off 4194304   (32768)
// idx: [B][N][K]   off 4227072   (655360 ints)
// wa : [C][O]      off 4882432   (4096)
// wb : [C][O]      off 4886528   (4096)

__global__ void k0_wprep(const float* __restrict__ W,
                         float* __restrict__ wa, float* __restrict__ wb) {
  int t = threadIdx.x;
  for (int i = t; i < NC * NO; i += 256) {
    int o = i & 63, c = i >> 6;
    float w1 = W[o * 128 + c];
    float w2 = W[o * 128 + 64 + c];
    wa[i] = w1 - w2;  // [c][o]
    wb[i] = w2;
  }
}

__global__ __launch_bounds__(256) void k1_feat(const float* __restrict__ x,
    const float* __restrict__ waT, const float* __restrict__ wbT,
    float* __restrict__ y1, float* __restrict__ y2, float* __restrict__ xxg) {
  __shared__ __align__(16) float xs[NC * 64];   // [c][n]
  __shared__ __align__(16) float wa[NC * NO];   // [c][o]
  __shared__ __align__(16) float wb[NC * NO];
  int t = threadIdx.x;
  int b = blockIdx.x >> 6;
  int gr0 = (blockIdx.x & 63) << 6;
  const float* xb = x + (size_t)b * NC * NN;
  #pragma unroll
  for (int k = 0; k < 4; ++k) {
    int i4 = t + k * 256;            // 0..1023
    int c = i4 >> 4, col4 = (i4 & 15) << 2;
    *(float4*)&xs[c * 64 + col4] = *(const float4*)&xb[(size_t)c * NN + gr0 + col4];
    *(float4*)&wa[c * 64 + col4] = *(const float4*)&waT[c * 64 + col4];
    *(float4*)&wb[c * 64 + col4] = *(const float4*)&wbT[c * 64 + col4];
  }
  __syncthreads();
  if (t < 64) {
    float s = 0.f;
    #pragma unroll
    for (int c = 0; c < NC; ++c) { float v = xs[c * 64 + t]; s = fmaf(v, v, s); }
    xxg[b * NN + gr0 + t] = s;
  }
  int o = t & 63, w = t >> 6;
  for (int j = 0; j < 16; ++j) {
    int n = j * 4 + w;
    float a1 = 0.f, a2 = 0.f;
    #pragma unroll
    for (int c = 0; c < NC; ++c) {
      float xv = xs[c * 64 + n];               // wave-uniform broadcast
      a1 = fmaf(wa[c * 64 + o], xv, a1);
      a2 = fmaf(wb[c * 64 + o], xv, a2);
    }
    size_t base = ((size_t)b * NN + gr0 + n) * NO + o;
    y1[base] = a1;
    y2[base] = a2;
  }
}

// ----- fused Gram + per-row exact top-K via 2-phase histogram select -----
__global__ __launch_bounds__(256) void k2_topk(const float* __restrict__ x,
    const float* __restrict__ xxg, int* __restrict__ idxg) {
  __shared__ __align__(16) float As[4096];      // [c][r] 16KB
  __shared__ __align__(16) float Bs[4096];      // [c][m] 16KB
  __shared__ __align__(16) float xxs[64];
  __shared__ float xxrs[64];
  __shared__ int thrB[64];
  __shared__ unsigned cnt[64];
  __shared__ __align__(16) unsigned un[8192];   // 32KB: phase A = hist u32[64][128];
                                                // phase B = keyL f32[64][80] (un[0..5119])
                                                //          + idxL u16[64][80] (un[5120..7679])
  int t = threadIdx.x;
  int b = blockIdx.x >> 6;
  int gr0 = (blockIdx.x & 63) << 6;
  const float* xb = x + (size_t)b * NC * NN;
  int ty = t >> 4, tx = t & 15;

  // init hist, stage A-tile (block's 64 rows) and row xx
  for (int i = t; i < 8192; i += 256) un[i] = 0;
  #pragma unroll
  for (int k = 0; k < 4; ++k) {
    int i4 = t + k * 256;
    int c = i4 >> 4, col4 = (i4 & 15) << 2;
    *(float4*)&As[c * 64 + col4] = *(const float4*)&xb[(size_t)c * NN + gr0 + col4];
  }
  if (t < 64) xxrs[t] = xxg[b * NN + gr0 + t];
  __syncthreads();

  float xr[4];
  #pragma unroll
  for (int i = 0; i < 4; ++i) xr[i] = xxrs[ty * 4 + i];

  // ---- phase A: Gram + per-row histogram of d2 ----
  for (int mt = 0; mt < 64; ++mt) {
    int gm0 = mt << 6;
    __syncthreads();
    #pragma unroll
    for (int k = 0; k < 4; ++k) {
      int i4 = t + k * 256;
      int c = i4 >> 4, col4 = (i4 & 15) << 2;
      *(float4*)&Bs[c * 64 + col4] = *(const float4*)&xb[(size_t)c * NN + gm0 + col4];
    }
    if (t < 16) *(float4*)&xxs[t * 4] = *(const float4*)&xxg[b * NN + gm0 + t * 4];
    __syncthreads();

    float acc[4][4];
    #pragma unroll
    for (int i = 0; i < 4; ++i)
      #pragma unroll
      for (int j = 0; j < 4; ++j) acc[i][j] = 0.f;
    #pragma unroll 8
    for (int c = 0; c < 64; ++c) {
      float4 av = *(const float4*)&As[c * 64 + ty * 4];
      float4 bv = *(const float4*)&Bs[c * 64 + tx * 4];
      float a_[4] = {av.x, av.y, av.z, av.w};
      float b_[4] = {bv.x, bv.y, bv.z, bv.w};
      #pragma unroll
      for (int i = 0; i < 4; ++i)
        #pragma unroll
        for (int j = 0; j < 4; ++j)
          acc[i][j] = fmaf(a_[i], b_[j], acc[i][j]);
    }
    float4 xxv = *(const float4*)&xxs[tx * 4];
    float xm[4] = {xxv.x, xxv.y, xxv.z, xxv.w};
    #pragma unroll
    for (int i = 0; i < 4; ++i) {
      int r = ty * 4 + i;
      #pragma unroll
      for (int j = 0; j < 4; ++j) {
        float d2 = fmaf(-2.f, acc[i][j], xr[i] + xm[j]);  // EXACT same expr as phase B
        int bb = (int)(d2 * 0.5f);
        bb = bb < 0 ? 0 : (bb > 127 ? 127 : bb);
        atomicAdd(&un[r * 128 + bb], 1u);
      }
    }
  }

  __syncthreads();  // all histogram atomics done
  if (t < 64) {
    int s = 0, bst = 127;
    for (int bb = 0; bb < 128; ++bb) { s += (int)un[t * 128 + bb]; if (s >= KK) { bst = bb; break; } }
    thrB[t] = bst;
    cnt[t] = 0;
  }
  __syncthreads();

  int thr_i[4];
  #pragma unroll
  for (int i = 0; i < 4; ++i) thr_i[i] = thrB[ty * 4 + i];
  float* keyL = (float*)un;                             // [64][80] -> un[0..5119]
  unsigned short* idxL = (unsigned short*)(un + 5120);  // [64][80] u16 -> un[5120..7679]

  // ---- phase B: recompute Gram (bit-identical), collect passing candidates ----
  for (int mt = 0; mt < 64; ++mt) {
    int gm0 = mt << 6;
    __syncthreads();
    #pragma unroll
    for (int k = 0; k < 4; ++k) {
      int i4 = t + k * 256;
      int c = i4 >> 4, col4 = (i4 & 15) << 2;
      *(float4*)&Bs[c * 64 + col4] = *(const float4*)&xb[(size_t)c * NN + gm0 + col4];
    }
    if (t < 16) *(float4*)&xxs[t * 4] = *(const float4*)&xxg[b * NN + gm0 + t * 4];
    __syncthreads();

    float acc[4][4];
    #pragma unroll
    for (int i = 0; i < 4; ++i)
      #pragma unroll
      for (int j = 0; j < 4; ++j) acc[i][j] = 0.f;
    #pragma unroll 8
    for (int c = 0; c < 64; ++c) {
      float4 av = *(const float4*)&As[c * 64 + ty * 4];
      float4 bv = *(const float4*)&Bs[c * 64 + tx * 4];
      float a_[4] = {av.x, av.y, av.z, av.w};
      float b_[4] = {bv.x, bv.y, bv.z, bv.w};
      #pragma unroll
      for (int i = 0; i < 4; ++i)
        #pragma unroll
        for (int j = 0; j < 4; ++j)
          acc[i][j] = fmaf(a_[i], b_[j], acc[i][j]);
    }
    float4 xxv = *(const float4*)&xxs[tx * 4];
    float xm[4] = {xxv.x, xxv.y, xxv.z, xxv.w};
    #pragma unroll
    for (int i = 0; i < 4; ++i) {
      int r = ty * 4 + i;
      #pragma unroll
      for (int j = 0; j < 4; ++j) {
        float d2 = fmaf(-2.f, acc[i][j], xr[i] + xm[j]);  // EXACT same expr as phase A
        int bb = (int)(d2 * 0.5f);
        bb = bb < 0 ? 0 : (bb > 127 ? 127 : bb);
        if (bb <= thr_i[i]) {
          unsigned slot = atomicAdd(&cnt[r], 1u);
          if (slot < CAP) {
            keyL[r * CAP + slot] = d2;
            idxL[r * CAP + slot] = (unsigned short)(gm0 + tx * 4 + j);
          }
        }
      }
    }
  }

  // ---- exact top-20 among ~25-35 survivors per row ----
  __syncthreads();
  if (t < 64) {
    int r = t;
    int c = (int)cnt[r]; if (c > CAP) c = CAP;
    float kv[KK]; int ki[KK];
    #pragma unroll
    for (int j = 0; j < KK; ++j) { kv[j] = 3.4e38f; ki[j] = 0; }
    for (int s = 0; s < c; ++s) {
      float k = keyL[r * CAP + s];
      int m = (int)idxL[r * CAP + s];
      bool ins = (k < kv[KK - 1]) || (k == kv[KK - 1] && m < ki[KK - 1]);
      if (ins) {
        #pragma unroll
        for (int j = KK - 1; j >= 1; --j) {
          bool sh = (k < kv[j - 1]) || (k == kv[j - 1] && m < ki[j - 1]);
          bool he = (k < kv[j]) || (k == kv[j] && m < ki[j]);
          float pv = kv[j - 1]; int pi = ki[j - 1];
          kv[j] = sh ? pv : (he ? k : kv[j]);
          ki[j] = sh ? pi : (he ? m : ki[j]);
        }
        if ((k < kv[0]) || (k == kv[0] && m < ki[0])) { kv[0] = k; ki[0] = m; }
      }
    }
    int* op = idxg + ((size_t)b * NN + gr0 + r) * KK;
    #pragma unroll
    for (int j = 0; j < KK; ++j) op[j] = ki[j];
  }
}

__global__ __launch_bounds__(256) void k3_out(const float* __restrict__ y1,
    const float* __restrict__ y2, const int* __restrict__ idxg,
    const float* __restrict__ gamma, const float* __restrict__ beta,
    const float* __restrict__ rmean, const float* __restrict__ rvar,
    float* __restrict__ out) {
  __shared__ int sidx[64 * KK];
  __shared__ float ot[64 * 65];  // [o][n], pad 65
  int t = threadIdx.x;
  int b = blockIdx.x >> 6;
  int gr0 = (blockIdx.x & 63) << 6;
  const int* ib = idxg + ((size_t)b * NN + gr0) * KK;
  for (int i = t; i < 64 * KK; i += 256) sidx[i] = ib[i];
  int l = t & 63, w = t >> 6;
  float sc = gamma[l] * rsqrtf(rvar[l] + EPSV);
  float tt = fmaf(-rmean[l], sc, beta[l]);
  __syncthreads();
  const float* y2b = y2 + (size_t)b * NN * NO;
  for (int rr = 0; rr < 16; ++rr) {
    int row = w * 16 + rr;
    float v1 = y1[((size_t)b * NN + gr0 + row) * NO + l];
    float best = -3.4e38f;
    #pragma unroll 4
    for (int k = 0; k < KK; ++k) {
      int m = sidx[row * KK + k];                 // wave-uniform broadcast
      float v = v1 + y2b[(size_t)m * NO + l];     // coalesced 256B gather
      v = fmaf(v, sc, tt);
      v = v >= 0.f ? v : SLOPE * v;
      best = fmaxf(best, v);
    }
    ot[l * 65 + row] = best;
  }
  __syncthreads();
  float* ob = out + (size_t)b * NO * NN;
  for (int i = t; i < 4096; i += 256) {
    int o = i >> 6, n = i & 63;
    ob[(size_t)o * NN + gr0 + n] = ot[o * 65 + n];  // coalesced
  }
}

extern "C" void kernel_launch(void* const* d_in, const int* in_sizes, int n_in,
                              void* d_out, int out_size, void* d_ws, size_t ws_size,
                              hipStream_t stream) {
  const float* x     = (const float*)d_in[0];
  const float* W     = (const float*)d_in[1];
  const float* gamma = (const float*)d_in[2];
  const float* beta  = (const float*)d_in[3];
  const float* rmean = (const float*)d_in[4];
  const float* rvar  = (const float*)d_in[5];
  float* ws  = (float*)d_ws;
  float* y1  = ws;
  float* y2  = ws + 2097152;
  float* xx  = ws + 4194304;
  int*   idx = (int*)(ws + 4227072);
  float* wa  = ws + 4882432;
  float* wb  = ws + 4886528;
  float* out = (float*)d_out;

  hipLaunchKernelGGL(k0_wprep, dim3(1),   dim3(256), 0, stream, W, wa, wb);
  hipLaunchKernelGGL(k1_feat,  dim3(512), dim3(256), 0, stream, x, wa, wb, y1, y2, xx);
  hipLaunchKernelGGL(k2_topk,  dim3(512), dim3(256), 0, stream, x, xx, idx);
  hipLaunchKernelGGL(k3_out,   dim3(512), dim3(256), 0, stream, y1, y2, idx,
                     gamma, beta, rmean, rvar, out);
}